// Round 1
// baseline (254.824 us; speedup 1.0000x reference)
//
#include <hip/hip_runtime.h>
#include <cstdint>
#include <cstddef>

#define NUM_C 21
#define NROW 336   // 21 classes * 16 images, row r = cls*16 + img

// ---------------- K1: bilinear label resize (513x513 -> 64x64) + per-image histogram ----
__global__ __launch_bounds__(256) void k1_resize_hist(const int* __restrict__ labels,
                                                      uint8_t* __restrict__ lab,
                                                      int* __restrict__ counts,
                                                      float* __restrict__ out) {
    int b = blockIdx.x;
    if (b == 0 && threadIdx.x == 0) out[0] = 0.0f;   // zero loss accumulator (K5 runs later in stream)
    __shared__ int hist[NUM_C];
    if (threadIdx.x < NUM_C) hist[threadIdx.x] = 0;
    __syncthreads();
    const int* L = labels + (size_t)b * 513 * 513;
    uint8_t* labB = lab + b * 4096;
    for (int it = 0; it < 16; ++it) {
        int p = it * 256 + threadIdx.x;
        int y = p >> 6, x = p & 63;
        // sample_f = (i+0.5)*513/64 - 0.5 ; 513/64 = 8.015625 exact in fp32.
        float sy = (y + 0.5f) * 8.015625f - 0.5f;   // in [3.507, 508.49] -> no clamp needed
        float sx = (x + 0.5f) * 8.015625f - 0.5f;
        int y0 = (int)sy; float fy = sy - (float)y0;
        int x0 = (int)sx; float fx = sx - (float)x0;
        const int* r0 = L + y0 * 513 + x0;
        float L00 = (float)r0[0],   L01 = (float)r0[1];
        float L10 = (float)r0[513], L11 = (float)r0[514];
        // all intermediates are exact dyadic rationals -> floor is bit-exact vs reference
        float v0 = (1.0f - fx) * L00 + fx * L01;
        float v1 = (1.0f - fx) * L10 + fx * L11;
        float val = (1.0f - fy) * v0 + fy * v1;
        int c = (int)val;                       // val >= 0 -> trunc == floor
        labB[p] = (uint8_t)c;
        atomicAdd(&hist[c], 1);
    }
    __syncthreads();
    if (threadIdx.x < NUM_C) counts[b * NUM_C + threadIdx.x] = hist[threadIdx.x];
}

// ---------------- K2: per-(image,class) masked feature pooling -> sums[336][512] --------
// wave per (b,d): lanes sweep 4096 pixels coalesced; class-indexed LDS accumulation,
// layout accum[c*64+lane] -> lane-private column, 2-way bank aliasing (free).
__global__ __launch_bounds__(256) void k2_sums(const float* __restrict__ feat,
                                               const uint8_t* __restrict__ lab,
                                               float* __restrict__ sums) {
    int b  = blockIdx.x >> 7;      // 128 d-groups per image
    int dg = blockIdx.x & 127;
    int t = threadIdx.x;
    int wv = t >> 6, lane = t & 63;
    __shared__ uint8_t labLds[4096];
    __shared__ float accum[4][NUM_C * 64];

    const uint32_t* labSrc = (const uint32_t*)(lab + b * 4096);
    uint32_t* labDst = (uint32_t*)labLds;
#pragma unroll
    for (int q = 0; q < 4; ++q) labDst[t + 256 * q] = labSrc[t + 256 * q];

    float* accFlat = &accum[0][0];
#pragma unroll
    for (int q = 0; q < NUM_C; ++q) accFlat[t + 256 * q] = 0.0f;
    __syncthreads();

    int d = dg * 4 + wv;
    const float* f = feat + ((size_t)(b * 512 + d)) * 4096;
    float* acc = accum[wv];
#pragma unroll 4
    for (int it = 0; it < 64; ++it) {
        int p = it * 64 + lane;
        float v = f[p];
        int c = labLds[p];
        acc[c * 64 + lane] += v;   // in-order LDS pipe: per-lane RMW is safe
    }
    // per-class cross-lane reduction
    for (int c = 0; c < NUM_C; ++c) {
        float v = acc[c * 64 + lane];
#pragma unroll
        for (int off = 32; off >= 1; off >>= 1) v += __shfl_xor(v, off, 64);
        if (lane == 0) sums[(size_t)(c * 16 + b) * 512 + d] = v;
    }
}

// ---------------- K3: inverse L2 norms of the 336 prototype rows ------------------------
__global__ __launch_bounds__(256) void k3_norms(const float* __restrict__ sums,
                                                float* __restrict__ invn) {
    int w = blockIdx.x * 4 + (threadIdx.x >> 6);
    int lane = threadIdx.x & 63;
    if (w >= NROW) return;
    const float4* s4 = (const float4*)(sums + (size_t)w * 512);
    float ss = 0.0f;
#pragma unroll
    for (int q = 0; q < 2; ++q) {
        float4 v = s4[lane + 64 * q];
        ss += v.x * v.x + v.y * v.y + v.z * v.z + v.w * v.w;
    }
#pragma unroll
    for (int off = 32; off >= 1; off >>= 1) ss += __shfl_xor(ss, off, 64);
    if (lane == 0) invn[w] = 1.0f / fmaxf(sqrtf(ss), 1e-12f);
}

// ---------------- K4: Gram of raw sums, k-split into 8 partial slabs --------------------
// grid (11,11,8), block 64. 32x32 tile, 4x4 per thread, k-slab of 64.
__global__ __launch_bounds__(64) void k4_gram(const float* __restrict__ sums,
                                              float* __restrict__ gpart) {
    int row0 = blockIdx.x * 32, col0 = blockIdx.y * 32, k0 = blockIdx.z * 64;
    __shared__ float A[32 * 66], Bt[32 * 66];   // pad 66 -> 2-way max on b64 reads (free)
    int t = threadIdx.x;
    int row = t >> 1, kk0 = (t & 1) * 32;
#pragma unroll
    for (int q = 0; q < 8; ++q) {
        int kk = kk0 + q * 4;
        int ra = row0 + row, rb = col0 + row;
        float4 va = (ra < NROW) ? *(const float4*)&sums[(size_t)ra * 512 + k0 + kk]
                                : make_float4(0.f, 0.f, 0.f, 0.f);
        float4 vb = (rb < NROW) ? *(const float4*)&sums[(size_t)rb * 512 + k0 + kk]
                                : make_float4(0.f, 0.f, 0.f, 0.f);
        *(float2*)&A[row * 66 + kk]      = make_float2(va.x, va.y);
        *(float2*)&A[row * 66 + kk + 2]  = make_float2(va.z, va.w);
        *(float2*)&Bt[row * 66 + kk]     = make_float2(vb.x, vb.y);
        *(float2*)&Bt[row * 66 + kk + 2] = make_float2(vb.z, vb.w);
    }
    __syncthreads();
    int ty = t >> 3, tx = t & 7;
    float acc[4][4] = {};
    for (int kk = 0; kk < 64; kk += 2) {
        float2 a[4], bb[4];
#pragma unroll
        for (int u = 0; u < 4; ++u) {
            a[u]  = *(const float2*)&A[(ty * 4 + u) * 66 + kk];
            bb[u] = *(const float2*)&Bt[(tx * 4 + u) * 66 + kk];
        }
#pragma unroll
        for (int u = 0; u < 4; ++u)
#pragma unroll
            for (int v = 0; v < 4; ++v)
                acc[u][v] += a[u].x * bb[v].x + a[u].y * bb[v].y;
    }
    float* gp = gpart + (size_t)blockIdx.z * (NROW * NROW);
#pragma unroll
    for (int u = 0; u < 4; ++u) {
        int r1 = row0 + ty * 4 + u;
        if (r1 >= NROW) continue;
#pragma unroll
        for (int v = 0; v < 4; ++v) {
            int r2 = col0 + tx * 4 + v;
            if (r2 < NROW) gp[(size_t)r1 * NROW + r2] = acc[u][v];
        }
    }
}

// ---------------- K5: per-class masked LSE loss, block per class ------------------------
// lse = logaddexp(lse_diag, lse_all) = M + log(sum_all e^{s-M} + sum_diag e^{s-M})
__global__ __launch_bounds__(256) void k5_loss(const float* __restrict__ gpart,
                                               const float* __restrict__ invn,
                                               const int* __restrict__ counts,
                                               float* __restrict__ out) {
    int c = blockIdx.x;
    int t = threadIdx.x;
    int wv = t >> 6, lane = t & 63;
    __shared__ float sRows[16 * NROW];
    __shared__ float invnL[NROW];
    __shared__ uint8_t presL[NROW];
    __shared__ float redM[4], redE[4], redD[4], redL[4];

    for (int r = t; r < NROW; r += 256) {
        invnL[r] = invn[r];
        int img = r & 15, cls = r >> 4;
        presL[r] = (counts[img * NUM_C + cls] > 0) ? 1 : 0;
    }
    __syncthreads();

    // build the 16 x 336 score block for this class (sum 8 gram partials inline)
    for (int i = 0; i < 16; ++i) {
        int r1 = c * 16 + i;
        bool rowValid = presL[r1] != 0;
        float in1 = invnL[r1];
        for (int r2 = t; r2 < NROW; r2 += 256) {
            float acc = 0.0f;
#pragma unroll
            for (int s = 0; s < 8; ++s)
                acc += gpart[(size_t)s * (NROW * NROW) + (size_t)r1 * NROW + r2];
            float sval = acc * in1 * invnL[r2] * 10.0f;   // /T, T=0.1
            sRows[i * NROW + r2] = (rowValid && presL[r2]) ? sval : -1e30f;
        }
    }
    __syncthreads();

    // pass 1: global max over valid entries
    float m = -1e30f;
    for (int idx = t; idx < 16 * NROW; idx += 256) m = fmaxf(m, sRows[idx]);
#pragma unroll
    for (int off = 32; off >= 1; off >>= 1) m = fmaxf(m, __shfl_xor(m, off, 64));
    if (lane == 0) redM[wv] = m;
    __syncthreads();
    m = fmaxf(fmaxf(redM[0], redM[1]), fmaxf(redM[2], redM[3]));

    int nc = 0;
    for (int j = 0; j < 16; ++j) nc += presL[c * 16 + j];
    if (nc == 0) return;   // class absent everywhere: contributes 0 (uniform exit)

    // pass 2: exp-sums + diag stats (sentinel -1e30 -> expf underflows to 0)
    float expSum = 0.0f, diagExp = 0.0f, diagLin = 0.0f;
    int dlo = c * 16, dhi = c * 16 + 16;
    for (int i = 0; i < 16; ++i) {
        for (int r2 = t; r2 < NROW; r2 += 256) {
            float s = sRows[i * NROW + r2];
            float e = expf(s - m);
            expSum += e;
            if (r2 >= dlo && r2 < dhi && s > -1e29f) { diagExp += e; diagLin += s; }
        }
    }
#pragma unroll
    for (int off = 32; off >= 1; off >>= 1) {
        expSum  += __shfl_xor(expSum, off, 64);
        diagExp += __shfl_xor(diagExp, off, 64);
        diagLin += __shfl_xor(diagLin, off, 64);
    }
    if (lane == 0) { redE[wv] = expSum; redD[wv] = diagExp; redL[wv] = diagLin; }
    __syncthreads();
    if (t == 0) {
        float E = redE[0] + redE[1] + redE[2] + redE[3];
        float D = redD[0] + redD[1] + redD[2] + redD[3];
        float Ln = redL[0] + redL[1] + redL[2] + redL[3];
        float lse = m + logf(E + D);
        float posMean = Ln / (float)(nc * nc);
        atomicAdd(out, lse - posMean);
    }
}

// ---------------- launcher --------------------------------------------------------------
extern "C" void kernel_launch(void* const* d_in, const int* in_sizes, int n_in,
                              void* d_out, int out_size, void* d_ws, size_t ws_size,
                              hipStream_t stream) {
    const float* features = (const float*)d_in[0];
    const int* labels = (const int*)d_in[1];
    char* ws = (char*)d_ws;

    uint8_t* lab  = (uint8_t*)ws;                                   // 65536 B
    int* counts   = (int*)(ws + 65536);                             // 1344 B (pad to 2048)
    float* sums   = (float*)(ws + 65536 + 2048);                    // 336*512*4 = 688128 B
    float* invn   = (float*)(ws + 65536 + 2048 + 688128);           // 1344 B (pad to 2048)
    float* gpart  = (float*)(ws + 65536 + 2048 + 688128 + 2048);    // 8*336*336*4 = 3612672 B
    float* out    = (float*)d_out;

    k1_resize_hist<<<16, 256, 0, stream>>>(labels, lab, counts, out);
    k2_sums<<<2048, 256, 0, stream>>>(features, lab, sums);
    k3_norms<<<84, 256, 0, stream>>>(sums, invn);
    k4_gram<<<dim3(11, 11, 8), 64, 0, stream>>>(sums, gpart);
    k5_loss<<<21, 256, 0, stream>>>(gpart, invn, counts, out);
}

// Round 2
// 231.262 us; speedup vs baseline: 1.1019x; 1.1019x over previous
//
#include <hip/hip_runtime.h>
#include <cstdint>
#include <cstddef>

#define NUM_C 21
#define NROW 336      // 21 classes * 16 images, row r = cls*16 + img
#define N2   (NROW * NROW)

// ---------------- K1: bilinear label resize (513x513 -> 64x64) + per-block histogram ----
// 256 blocks (16 images x 16 strips), 1 pixel/thread. Per-block hist -> private slot in
// countsPart (no global atomics, no zeroing kernel needed).
__global__ __launch_bounds__(256) void k1_resize_hist(const int* __restrict__ labels,
                                                      uint8_t* __restrict__ lab,
                                                      int* __restrict__ countsPart,
                                                      float* __restrict__ out) {
    int b = blockIdx.x >> 4, strip = blockIdx.x & 15;
    if (blockIdx.x == 0 && threadIdx.x == 0) out[0] = 0.0f;  // K5 (later in stream) accumulates
    __shared__ int hist[NUM_C];
    if (threadIdx.x < NUM_C) hist[threadIdx.x] = 0;
    __syncthreads();

    int p = strip * 256 + threadIdx.x;      // pixel in [0,4096)
    int y = p >> 6, x = p & 63;
    const int* L = labels + (size_t)b * 263169;   // 513*513
    // sample_f = (i+0.5)*513/64 - 0.5 ; 513/64 = 8.015625 exact in fp32; range [3.5,508.5] -> no clamp
    float sy = (y + 0.5f) * 8.015625f - 0.5f;
    float sx = (x + 0.5f) * 8.015625f - 0.5f;
    int y0 = (int)sy; float fy = sy - (float)y0;
    int x0 = (int)sx; float fx = sx - (float)x0;
    const int* r0 = L + y0 * 513 + x0;
    float L00 = (float)r0[0],   L01 = (float)r0[1];
    float L10 = (float)r0[513], L11 = (float)r0[514];
    // exact dyadic arithmetic -> floor bit-exact vs reference (verified absmax 0.0)
    float v0 = (1.0f - fx) * L00 + fx * L01;
    float v1 = (1.0f - fx) * L10 + fx * L11;
    float val = (1.0f - fy) * v0 + fy * v1;
    int c = (int)val;
    lab[b * 4096 + p] = (uint8_t)c;
    atomicAdd(&hist[c], 1);
    __syncthreads();
    if (threadIdx.x < NUM_C) countsPart[blockIdx.x * NUM_C + threadIdx.x] = hist[threadIdx.x];
}

// ---------------- K2: masked feature pooling -> sums[336][512] --------------------------
// wave per (b,d): float4 loads (16B/lane), packed labels read as dword, class-indexed LDS
// accumulation accum[c*64+lane] (lane-private column -> 2-way bank aliasing, free).
__global__ __launch_bounds__(256) void k2_sums(const float* __restrict__ feat,
                                               const uint8_t* __restrict__ lab,
                                               float* __restrict__ sums) {
    int b  = blockIdx.x >> 7;      // 128 d-groups per image
    int dg = blockIdx.x & 127;
    int t = threadIdx.x;
    int wv = t >> 6, lane = t & 63;
    __shared__ uint32_t lab4[1024];
    __shared__ float accum[4][NUM_C * 64];

    const uint32_t* labSrc = (const uint32_t*)(lab + b * 4096);
#pragma unroll
    for (int q = 0; q < 4; ++q) lab4[t + 256 * q] = labSrc[t + 256 * q];
    float* accFlat = &accum[0][0];
#pragma unroll
    for (int q = 0; q < NUM_C; ++q) accFlat[t + 256 * q] = 0.0f;
    __syncthreads();

    int d = dg * 4 + wv;
    const float4* f4 = (const float4*)(feat + ((size_t)(b * 512 + d)) * 4096);
    float* acc = accum[wv];
#pragma unroll 4
    for (int it = 0; it < 16; ++it) {
        int p4 = it * 64 + lane;
        float4 v = f4[p4];
        uint32_t l4 = lab4[p4];
        acc[(l4 & 255u) * 64 + lane]         += v.x;
        acc[((l4 >> 8) & 255u) * 64 + lane]  += v.y;
        acc[((l4 >> 16) & 255u) * 64 + lane] += v.z;
        acc[(l4 >> 24) * 64 + lane]          += v.w;
    }
    // per-class cross-lane reduction
    for (int c = 0; c < NUM_C; ++c) {
        float v = acc[c * 64 + lane];
#pragma unroll
        for (int off = 32; off >= 1; off >>= 1) v += __shfl_xor(v, off, 64);
        if (lane == 0) sums[(size_t)(c * 16 + b) * 512 + d] = v;
    }
}

// ---------------- K4: Gram of raw sums, k-split into 8 partial slabs --------------------
// grid (11,11,8), block 64. 32x32 tile, 4x4 per thread, k-slab of 64.
__global__ __launch_bounds__(64) void k4_gram(const float* __restrict__ sums,
                                              float* __restrict__ gpart) {
    int row0 = blockIdx.x * 32, col0 = blockIdx.y * 32, k0 = blockIdx.z * 64;
    __shared__ float A[32 * 66], Bt[32 * 66];
    int t = threadIdx.x;
    int row = t >> 1, kk0 = (t & 1) * 32;
#pragma unroll
    for (int q = 0; q < 8; ++q) {
        int kk = kk0 + q * 4;
        int ra = row0 + row, rb = col0 + row;
        float4 va = (ra < NROW) ? *(const float4*)&sums[(size_t)ra * 512 + k0 + kk]
                                : make_float4(0.f, 0.f, 0.f, 0.f);
        float4 vb = (rb < NROW) ? *(const float4*)&sums[(size_t)rb * 512 + k0 + kk]
                                : make_float4(0.f, 0.f, 0.f, 0.f);
        *(float2*)&A[row * 66 + kk]      = make_float2(va.x, va.y);
        *(float2*)&A[row * 66 + kk + 2]  = make_float2(va.z, va.w);
        *(float2*)&Bt[row * 66 + kk]     = make_float2(vb.x, vb.y);
        *(float2*)&Bt[row * 66 + kk + 2] = make_float2(vb.z, vb.w);
    }
    __syncthreads();
    int ty = t >> 3, tx = t & 7;
    float acc[4][4] = {};
    for (int kk = 0; kk < 64; kk += 2) {
        float2 a[4], bb[4];
#pragma unroll
        for (int u = 0; u < 4; ++u) {
            a[u]  = *(const float2*)&A[(ty * 4 + u) * 66 + kk];
            bb[u] = *(const float2*)&Bt[(tx * 4 + u) * 66 + kk];
        }
#pragma unroll
        for (int u = 0; u < 4; ++u)
#pragma unroll
            for (int v = 0; v < 4; ++v)
                acc[u][v] += a[u].x * bb[v].x + a[u].y * bb[v].y;
    }
    float* gp = gpart + (size_t)blockIdx.z * N2;
#pragma unroll
    for (int u = 0; u < 4; ++u) {
        int r1 = row0 + ty * 4 + u;
        if (r1 >= NROW) continue;
#pragma unroll
        for (int v = 0; v < 4; ++v) {
            int r2 = col0 + tx * 4 + v;
            if (r2 < NROW) gp[(size_t)r1 * NROW + r2] = acc[u][v];
        }
    }
}

// ---------------- K5: per-class masked LSE loss, single pass ----------------------------
// invn recomputed from the Gram diagonal (||row||^2 = G[r][r]); presence from countsPart.
// Fixed LSE shift m=10: scores = 10*cosine <= 10, exp(s-10) in [e^-20, 1] -> no overflow,
// matches exact-max LSE to ~1e-6 (threshold 5.16).
__global__ __launch_bounds__(512) void k5_loss(const float* __restrict__ gpart,
                                               const int* __restrict__ countsPart,
                                               float* __restrict__ out) {
    int c = blockIdx.x, t = threadIdx.x;
    int wv = t >> 6, lane = t & 63;
    __shared__ float invnL[NROW];
    __shared__ uint8_t presL[NROW];
    __shared__ float redE[8], redD[8], redL[8];

    for (int r = t; r < NROW; r += 512) {
        float ss = 0.0f;
#pragma unroll
        for (int s = 0; s < 8; ++s) ss += gpart[(size_t)s * N2 + (size_t)r * 337];
        invnL[r] = 1.0f / fmaxf(sqrtf(ss), 1e-12f);
        int img = r & 15, cls = r >> 4;
        int cnt = 0;
#pragma unroll
        for (int s = 0; s < 16; ++s) cnt += countsPart[(img * 16 + s) * NUM_C + cls];
        presL[r] = cnt > 0 ? 1 : 0;
    }
    __syncthreads();

    int nc = 0;
#pragma unroll
    for (int j = 0; j < 16; ++j) nc += presL[c * 16 + j];
    if (nc == 0) return;   // class absent in all images: contributes 0 (uniform exit)

    float eS = 0.0f, dE = 0.0f, dL = 0.0f;
    for (int idx = t; idx < 16 * NROW; idx += 512) {
        int i = idx / NROW, r2 = idx - i * NROW;
        int r1 = c * 16 + i;
        float g = 0.0f;
#pragma unroll
        for (int s = 0; s < 8; ++s) g += gpart[(size_t)s * N2 + (size_t)r1 * NROW + r2];
        if (presL[r1] && presL[r2]) {
            float sv = g * invnL[r1] * invnL[r2] * 10.0f;   // /T, T=0.1
            float e = expf(sv - 10.0f);
            eS += e;
            if ((r2 >> 4) == c) { dE += e; dL += sv; }      // diag block (appears twice in logits)
        }
    }
#pragma unroll
    for (int off = 32; off >= 1; off >>= 1) {
        eS += __shfl_xor(eS, off, 64);
        dE += __shfl_xor(dE, off, 64);
        dL += __shfl_xor(dL, off, 64);
    }
    if (lane == 0) { redE[wv] = eS; redD[wv] = dE; redL[wv] = dL; }
    __syncthreads();
    if (t == 0) {
        float E = 0, D = 0, Ln = 0;
#pragma unroll
        for (int w = 0; w < 8; ++w) { E += redE[w]; D += redD[w]; Ln += redL[w]; }
        float lse = 10.0f + logf(E + D);
        float posMean = Ln / (float)(nc * nc);
        atomicAdd(out, lse - posMean);
    }
}

// ---------------- launcher --------------------------------------------------------------
extern "C" void kernel_launch(void* const* d_in, const int* in_sizes, int n_in,
                              void* d_out, int out_size, void* d_ws, size_t ws_size,
                              hipStream_t stream) {
    const float* features = (const float*)d_in[0];
    const int* labels = (const int*)d_in[1];
    char* ws = (char*)d_ws;

    uint8_t* lab    = (uint8_t*)ws;                          // 65536 B
    int* countsPart = (int*)(ws + 65536);                    // 256*21*4 = 21504 B
    float* sums     = (float*)(ws + 65536 + 21504);          // 336*512*4 = 688128 B
    float* gpart    = (float*)(ws + 65536 + 21504 + 688128); // 8*336*336*4 = 3612672 B
    float* out      = (float*)d_out;

    k1_resize_hist<<<256, 256, 0, stream>>>(labels, lab, countsPart, out);
    k2_sums<<<2048, 256, 0, stream>>>(features, lab, sums);
    k4_gram<<<dim3(11, 11, 8), 64, 0, stream>>>(sums, gpart);
    k5_loss<<<21, 512, 0, stream>>>(gpart, countsPart, out);
}